// Round 1
// baseline (2803.964 us; speedup 1.0000x reference)
//
#include <hip/hip_runtime.h>
#include <math.h>

#define NEGF (-1.0e9f)

// Kernel A: segment boundaries from sorted batch_index.
// seg[b] = first muon index with batch_index >= b ; seg[B] = M.
__global__ void seg_bounds_kernel(const int* __restrict__ bi, int M, int B,
                                  int* __restrict__ seg) {
    int m = blockIdx.x * blockDim.x + threadIdx.x;
    if (m >= M) return;
    int cur = bi[m];
    if (m == 0) {
        for (int b = 0; b <= cur; ++b) seg[b] = 0;
    } else {
        int prev = bi[m - 1];
        for (int b = prev + 1; b <= cur; ++b) seg[b] = m;
    }
    if (m == M - 1) {
        for (int b = cur + 1; b <= B; ++b) seg[b] = M;
    }
}

// Kernel B: one block per batch. Fused point-net -> segment max -> decision net.
__global__ __launch_bounds__(256, 4) void critic_kernel(
    const float* __restrict__ muons,   // [M,3]
    const float* __restrict__ conds,   // [B,4]
    const int*   __restrict__ seg,     // [B+1]
    const float* __restrict__ w1,      // [7,64]
    const float* __restrict__ b1,      // [64]
    const float* __restrict__ w2,      // [64,128]
    const float* __restrict__ b2,      // [128]
    const float* __restrict__ w3,      // [132,128]
    const float* __restrict__ b3,      // [128]
    const float* __restrict__ w4,      // [128]
    const float* __restrict__ b4,      // [1]
    float* __restrict__ out,           // [B]
    float scale)
{
    __shared__ float w1t[64 * 8];      // [k][i], i<7: w1[i][k], i==7: b1[k]
    __shared__ float w2s[64 * 128];    // row-major [k][j]
    __shared__ float b2s[128];
    __shared__ float wavemax[4][128];
    __shared__ float din[132];
    __shared__ float red[2];

    const int tid  = threadIdx.x;
    const int b    = blockIdx.x;
    const int wave = tid >> 6;
    const int lane = tid & 63;

    // ---- stage weights into LDS ----
    for (int idx = tid; idx < 512; idx += 256) {
        int k = idx >> 3, i = idx & 7;
        w1t[idx] = (i < 7) ? w1[i * 64 + k] : b1[k];
    }
    for (int idx = tid; idx < 8192; idx += 256) w2s[idx] = w2[idx];
    if (tid < 128) b2s[tid] = b2[tid];
    {
        float* wm = &wavemax[0][0];
        for (int idx = tid; idx < 512; idx += 256) wm[idx] = NEGF;
    }
    __syncthreads();

    const int start = seg[b];
    const int end   = seg[b + 1];

    float xin[8];
    xin[3] = conds[b * 4 + 0];
    xin[4] = conds[b * 4 + 1];
    xin[5] = conds[b * 4 + 2];
    xin[6] = conds[b * 4 + 3];
    xin[7] = 1.0f;

    const int nIter = (end - start + 255) >> 8;
    for (int it = 0; it < nIter; ++it) {
        const int m = start + it * 256 + tid;
        const bool active = (m < end);
        if (active) {
            xin[0] = muons[m * 3 + 0];
            xin[1] = muons[m * 3 + 1];
            xin[2] = muons[m * 3 + 2];
        } else {
            xin[0] = 0.0f; xin[1] = 0.0f; xin[2] = 0.0f;
        }

        // layer 1: h1[64] = leaky(xin . w1 + b1)
        float h1[64];
        #pragma unroll
        for (int k = 0; k < 64; ++k) {
            const float* wk = &w1t[k * 8];
            float s = 0.0f;
            #pragma unroll
            for (int i = 0; i < 8; ++i) s = fmaf(xin[i], wk[i], s);
            h1[k] = fmaxf(s, 0.2f * s);
        }

        // layer 2 in 8 chunks of 16 outputs, then wave max-reduce
        #pragma unroll 1
        for (int c = 0; c < 8; ++c) {
            float acc[16];
            #pragma unroll
            for (int j = 0; j < 16; ++j) acc[j] = b2s[c * 16 + j];
            #pragma unroll
            for (int k = 0; k < 64; ++k) {
                const float hk = h1[k];
                const float* wrow = &w2s[k * 128 + c * 16];
                #pragma unroll
                for (int j = 0; j < 16; ++j) acc[j] = fmaf(hk, wrow[j], acc[j]);
            }
            #pragma unroll
            for (int j = 0; j < 16; ++j) {
                float v = fmaxf(acc[j], 0.2f * acc[j]);
                acc[j] = active ? v : NEGF;
            }
            // butterfly max across the 64-lane wave
            #pragma unroll
            for (int j = 0; j < 16; ++j) {
                float v = acc[j];
                #pragma unroll
                for (int s = 1; s < 64; s <<= 1)
                    v = fmaxf(v, __shfl_xor(v, s, 64));
                acc[j] = v;
            }
            if (lane == 0) {
                #pragma unroll
                for (int j = 0; j < 16; ++j) {
                    float* p = &wavemax[wave][c * 16 + j];
                    *p = fmaxf(*p, acc[j]);
                }
            }
        }
    }
    __syncthreads();

    // ---- cross-wave max + decision input ----
    if (tid < 128) {
        float gm = wavemax[0][tid];
        gm = fmaxf(gm, wavemax[1][tid]);
        gm = fmaxf(gm, wavemax[2][tid]);
        gm = fmaxf(gm, wavemax[3][tid]);
        gm = fmaxf(gm, NEGF);
        din[tid] = gm;
        if (tid < 4) din[128 + tid] = conds[b * 4 + tid];
    }
    __syncthreads();

    // ---- decision net ----
    float part = 0.0f;
    if (tid < 128) {
        float g = b3[tid];
        #pragma unroll 4
        for (int i = 0; i < 132; ++i)
            g = fmaf(din[i], w3[i * 128 + tid], g);
        g = fmaxf(g, 0.2f * g);
        part = g * w4[tid];
    }
    #pragma unroll
    for (int s = 1; s < 64; s <<= 1)
        part += __shfl_xor(part, s, 64);
    if (tid == 0)  red[0] = part;
    if (tid == 64) red[1] = part;
    __syncthreads();
    if (tid == 0) {
        float sc = (red[0] + red[1] + b4[0]) * scale;
        out[b] = fminf(fmaxf(sc, -1000.0f), 1000.0f);
    }
}

extern "C" void kernel_launch(void* const* d_in, const int* in_sizes, int n_in,
                              void* d_out, int out_size, void* d_ws, size_t ws_size,
                              hipStream_t stream) {
    const float* muons = (const float*)d_in[0];
    const int*   bidx  = (const int*)d_in[1];
    const float* conds = (const float*)d_in[2];
    // d_in[3] = batch_size scalar (derive B from conditions instead)
    const float* w1 = (const float*)d_in[4];
    const float* b1 = (const float*)d_in[5];
    const float* w2 = (const float*)d_in[6];
    const float* b2 = (const float*)d_in[7];
    const float* w3 = (const float*)d_in[8];
    const float* b3 = (const float*)d_in[9];
    const float* w4 = (const float*)d_in[10];
    const float* b4 = (const float*)d_in[11];

    const int M = in_sizes[0] / 3;
    const int B = in_sizes[2] / 4;
    int* seg = (int*)d_ws;  // (B+1) ints
    const float scale = 1.0f / fmaxf(1.0f, sqrtf((float)B));

    seg_bounds_kernel<<<(M + 255) / 256, 256, 0, stream>>>(bidx, M, B, seg);
    critic_kernel<<<B, 256, 0, stream>>>(muons, conds, seg,
                                         w1, b1, w2, b2, w3, b3, w4, b4,
                                         (float*)d_out, scale);
}

// Round 2
// 1766.803 us; speedup vs baseline: 1.5870x; 1.5870x over previous
//
#include <hip/hip_runtime.h>
#include <math.h>

#define NEGF (-1.0e9f)

// Kernel A: segment boundaries from sorted batch_index.
// seg[b] = first muon index with batch_index >= b ; seg[B] = M.
__global__ void seg_bounds_kernel(const int* __restrict__ bi, int M, int B,
                                  int* __restrict__ seg) {
    int m = blockIdx.x * blockDim.x + threadIdx.x;
    if (m >= M) return;
    int cur = bi[m];
    if (m == 0) {
        for (int b = 0; b <= cur; ++b) seg[b] = 0;
    } else {
        int prev = bi[m - 1];
        for (int b = prev + 1; b <= cur; ++b) seg[b] = m;
    }
    if (m == M - 1) {
        for (int b = cur + 1; b <= B; ++b) seg[b] = M;
    }
}

// Kernel B: one 128-thread block per batch. Fused point-net -> segment max ->
// decision net.
// __launch_bounds__(128,2): 2 waves/EU min -> 256 VGPR cap, so h1[64]+acc[16]
// stay in registers (R1's 64-VGPR spill produced 8.7 GB of scratch traffic).
// LDS ~36 KB -> 4 blocks/CU = 8 waves/CU; VGPR pool 8*256 = 2048 fits exactly.
__global__ __launch_bounds__(128, 2) void critic_kernel(
    const float* __restrict__ muons,   // [M,3]
    const float* __restrict__ conds,   // [B,4]
    const int*   __restrict__ seg,     // [B+1]
    const float* __restrict__ w1,      // [7,64]
    const float* __restrict__ b1,      // [64]
    const float* __restrict__ w2,      // [64,128]
    const float* __restrict__ b2,      // [128]
    const float* __restrict__ w3,      // [132,128]
    const float* __restrict__ b3,      // [128]
    const float* __restrict__ w4,      // [128]
    const float* __restrict__ b4,      // [1]
    float* __restrict__ out,           // [B]
    float scale)
{
    __shared__ float w1t[64 * 8];      // [k][i], i<7: w1[i][k], i==7: b1[k]
    __shared__ float w2s[64 * 128];    // row-major [k][j]
    __shared__ float b2s[128];
    __shared__ float wavemax[2][128];
    __shared__ float din[132];
    __shared__ float red[2];

    const int tid  = threadIdx.x;
    const int b    = blockIdx.x;
    const int wave = tid >> 6;
    const int lane = tid & 63;

    // ---- stage weights into LDS ----
    for (int idx = tid; idx < 512; idx += 128) {
        int k = idx >> 3, i = idx & 7;
        w1t[idx] = (i < 7) ? w1[i * 64 + k] : b1[k];
    }
    for (int idx = tid; idx < 8192; idx += 128) w2s[idx] = w2[idx];
    b2s[tid] = b2[tid];
    wavemax[0][tid] = NEGF;
    wavemax[1][tid] = NEGF;
    __syncthreads();

    const int start = seg[b];
    const int end   = seg[b + 1];

    float xin[8];
    xin[3] = conds[b * 4 + 0];
    xin[4] = conds[b * 4 + 1];
    xin[5] = conds[b * 4 + 2];
    xin[6] = conds[b * 4 + 3];
    xin[7] = 1.0f;

    for (int m0 = start; m0 < end; m0 += 128) {
        const int m = m0 + tid;
        const bool active = (m < end);
        if (active) {
            xin[0] = muons[m * 3 + 0];
            xin[1] = muons[m * 3 + 1];
            xin[2] = muons[m * 3 + 2];
        } else {
            xin[0] = 0.0f; xin[1] = 0.0f; xin[2] = 0.0f;
        }

        // layer 1: h1[64] = leaky(xin . w1 + b1)
        float h1[64];
        #pragma unroll
        for (int k = 0; k < 64; ++k) {
            const float* wk = &w1t[k * 8];
            float s = 0.0f;
            #pragma unroll
            for (int i = 0; i < 8; ++i) s = fmaf(xin[i], wk[i], s);
            h1[k] = fmaxf(s, 0.2f * s);
        }

        // layer 2 in 8 chunks of 16 outputs, then wave max-reduce
        #pragma unroll 1
        for (int c = 0; c < 8; ++c) {
            float acc[16];
            #pragma unroll
            for (int j = 0; j < 16; ++j) acc[j] = b2s[c * 16 + j];
            #pragma unroll
            for (int k = 0; k < 64; ++k) {
                const float hk = h1[k];
                const float* wrow = &w2s[k * 128 + c * 16];
                #pragma unroll
                for (int j = 0; j < 16; ++j) acc[j] = fmaf(hk, wrow[j], acc[j]);
            }
            #pragma unroll
            for (int j = 0; j < 16; ++j) {
                float v = fmaxf(acc[j], 0.2f * acc[j]);
                acc[j] = active ? v : NEGF;
            }
            // butterfly max across the 64-lane wave
            #pragma unroll
            for (int j = 0; j < 16; ++j) {
                float v = acc[j];
                #pragma unroll
                for (int s = 1; s < 64; s <<= 1)
                    v = fmaxf(v, __shfl_xor(v, s, 64));
                acc[j] = v;
            }
            if (lane == 0) {
                #pragma unroll
                for (int j = 0; j < 16; ++j) {
                    float* p = &wavemax[wave][c * 16 + j];
                    *p = fmaxf(*p, acc[j]);
                }
            }
        }
    }
    __syncthreads();

    // ---- cross-wave max + decision input ----
    {
        float gm = fmaxf(wavemax[0][tid], wavemax[1][tid]);
        gm = fmaxf(gm, NEGF);
        din[tid] = gm;
        if (tid < 4) din[128 + tid] = conds[b * 4 + tid];
    }
    __syncthreads();

    // ---- decision net: all 128 threads, one output each ----
    float g = b3[tid];
    #pragma unroll 4
    for (int i = 0; i < 132; ++i)
        g = fmaf(din[i], w3[i * 128 + tid], g);
    g = fmaxf(g, 0.2f * g);
    float part = g * w4[tid];
    #pragma unroll
    for (int s = 1; s < 64; s <<= 1)
        part += __shfl_xor(part, s, 64);
    if (lane == 0) red[wave] = part;
    __syncthreads();
    if (tid == 0) {
        float sc = (red[0] + red[1] + b4[0]) * scale;
        out[b] = fminf(fmaxf(sc, -1000.0f), 1000.0f);
    }
}

extern "C" void kernel_launch(void* const* d_in, const int* in_sizes, int n_in,
                              void* d_out, int out_size, void* d_ws, size_t ws_size,
                              hipStream_t stream) {
    const float* muons = (const float*)d_in[0];
    const int*   bidx  = (const int*)d_in[1];
    const float* conds = (const float*)d_in[2];
    // d_in[3] = batch_size scalar (derive B from conditions instead)
    const float* w1 = (const float*)d_in[4];
    const float* b1 = (const float*)d_in[5];
    const float* w2 = (const float*)d_in[6];
    const float* b2 = (const float*)d_in[7];
    const float* w3 = (const float*)d_in[8];
    const float* b3 = (const float*)d_in[9];
    const float* w4 = (const float*)d_in[10];
    const float* b4 = (const float*)d_in[11];

    const int M = in_sizes[0] / 3;
    const int B = in_sizes[2] / 4;
    int* seg = (int*)d_ws;  // (B+1) ints
    const float scale = 1.0f / fmaxf(1.0f, sqrtf((float)B));

    seg_bounds_kernel<<<(M + 255) / 256, 256, 0, stream>>>(bidx, M, B, seg);
    critic_kernel<<<B, 128, 0, stream>>>(muons, conds, seg,
                                         w1, b1, w2, b2, w3, b3, w4, b4,
                                         (float*)d_out, scale);
}

// Round 5
// 679.001 us; speedup vs baseline: 4.1295x; 2.6021x over previous
//
#include <hip/hip_runtime.h>
#include <math.h>

#define NEGF (-1.0e9f)

// Kernel A: segment boundaries from sorted batch_index.
// seg[b] = first muon index with batch_index >= b ; seg[B] = M.
__global__ void seg_bounds_kernel(const int* __restrict__ bi, int M, int B,
                                  int* __restrict__ seg) {
    int m = blockIdx.x * blockDim.x + threadIdx.x;
    if (m >= M) return;
    int cur = bi[m];
    if (m == 0) {
        for (int b = 0; b <= cur; ++b) seg[b] = 0;
    } else {
        int prev = bi[m - 1];
        for (int b = prev + 1; b <= cur; ++b) seg[b] = m;
    }
    if (m == M - 1) {
        for (int b = cur + 1; b <= B; ++b) seg[b] = M;
    }
}

// One 128-thread block per batch.
// Phase A: layer-1 (7->64) computed in 4-wide chunks, streamed to LDS h1s.
//          (2 threads per muon, 32 h1 outputs each -> only 4 live h1 regs:
//           this is what kills R2's 1.98 GB scratch-spill traffic.)
// Phase B: layer-2 (64->128) with w2 DISTRIBUTED IN REGISTERS: lane tid owns
//          output column j=tid (w2col[64]). h1 rows read wave-uniform from
//          LDS (broadcast, conflict-free). Segment-max folded immediately.
// LDS ~20 KB + VGPR<=128  ->  8 blocks/CU = 4 waves/SIMD (vs R2's 2).
__global__ __launch_bounds__(128, 4) void critic_kernel(
    const float* __restrict__ muons,   // [M,3]
    const float* __restrict__ conds,   // [B,4]
    const int*   __restrict__ seg,     // [B+1]
    const float* __restrict__ w1,      // [7,64]
    const float* __restrict__ b1,      // [64]
    const float* __restrict__ w2,      // [64,128]
    const float* __restrict__ b2,      // [128]
    const float* __restrict__ w3,      // [132,128]
    const float* __restrict__ b3,      // [128]
    const float* __restrict__ w4,      // [128]
    const float* __restrict__ b4,      // [1]
    float* __restrict__ out,           // [B]
    float scale)
{
    // stride 68 floats = 272 B: 16B-aligned rows for b128, bank-spread writes
    __shared__ __align__(16) float w1t[64 * 8];   // [k][i], i<7: w1[i][k], i==7: b1[k]
    __shared__ __align__(16) float h1s[64][68];
    __shared__ float din[132];
    __shared__ float red[2];

    const int tid  = threadIdx.x;
    const int b    = blockIdx.x;
    const int wave = tid >> 6;
    const int lane = tid & 63;

    // ---- stage w1(+b1) into LDS ----
    for (int idx = tid; idx < 512; idx += 128) {
        int k = idx >> 3, i = idx & 7;
        w1t[idx] = (i < 7) ? w1[i * 64 + k] : b1[k];
    }

    // ---- per-lane w2 column j = tid (coalesced per-k across lanes) ----
    float w2col[64];
    #pragma unroll
    for (int k = 0; k < 64; ++k) w2col[k] = w2[k * 128 + tid];
    const float b2j = b2[tid];

    const float c0 = conds[b * 4 + 0];
    const float c1 = conds[b * 4 + 1];
    const float c2 = conds[b * 4 + 2];
    const float c3 = conds[b * 4 + 3];

    __syncthreads();

    const int start = seg[b];
    const int end   = seg[b + 1];

    float gmax = NEGF;
    const int mslot = tid >> 1;   // 0..63 across the block
    const int half  = tid & 1;    // which 32 h1 outputs this thread computes

    for (int m0 = start; m0 < end; m0 += 64) {
        const int cnt = min(64, end - m0);

        // ---- phase A: layer 1 -> LDS ----
        if (mslot < cnt) {
            const int gm = m0 + mslot;
            const float x0 = muons[gm * 3 + 0];
            const float x1 = muons[gm * 3 + 1];
            const float x2 = muons[gm * 3 + 2];
            #pragma unroll
            for (int kk = 0; kk < 32; kk += 4) {
                float hv[4];
                #pragma unroll
                for (int u = 0; u < 4; ++u) {
                    const float* wk = &w1t[(half * 32 + kk + u) * 8];
                    float s = wk[7];
                    s = fmaf(x0, wk[0], s);
                    s = fmaf(x1, wk[1], s);
                    s = fmaf(x2, wk[2], s);
                    s = fmaf(c0, wk[3], s);
                    s = fmaf(c1, wk[4], s);
                    s = fmaf(c2, wk[5], s);
                    s = fmaf(c3, wk[6], s);
                    hv[u] = fmaxf(s, 0.2f * s);
                }
                *(float4*)&h1s[mslot][half * 32 + kk] =
                    make_float4(hv[0], hv[1], hv[2], hv[3]);
            }
        }
        __syncthreads();

        // ---- phase B: layer 2, one output column per lane, max-fold ----
        int m = 0;
        for (; m + 2 <= cnt; m += 2) {            // 2 muons: independent FMA chains
            float acc0 = b2j, acc1 = b2j;
            const float* hr0 = &h1s[m][0];
            const float* hr1 = &h1s[m + 1][0];
            #pragma unroll
            for (int kk = 0; kk < 16; ++kk) {
                const float4 hv0 = *(const float4*)&hr0[kk * 4];
                const float4 hv1 = *(const float4*)&hr1[kk * 4];
                acc0 = fmaf(hv0.x, w2col[kk * 4 + 0], acc0);
                acc1 = fmaf(hv1.x, w2col[kk * 4 + 0], acc1);
                acc0 = fmaf(hv0.y, w2col[kk * 4 + 1], acc0);
                acc1 = fmaf(hv1.y, w2col[kk * 4 + 1], acc1);
                acc0 = fmaf(hv0.z, w2col[kk * 4 + 2], acc0);
                acc1 = fmaf(hv1.z, w2col[kk * 4 + 2], acc1);
                acc0 = fmaf(hv0.w, w2col[kk * 4 + 3], acc0);
                acc1 = fmaf(hv1.w, w2col[kk * 4 + 3], acc1);
            }
            gmax = fmaxf(gmax, fmaxf(acc0, 0.2f * acc0));
            gmax = fmaxf(gmax, fmaxf(acc1, 0.2f * acc1));
        }
        if (m < cnt) {
            float acc0 = b2j;
            const float* hr0 = &h1s[m][0];
            #pragma unroll
            for (int kk = 0; kk < 16; ++kk) {
                const float4 hv0 = *(const float4*)&hr0[kk * 4];
                acc0 = fmaf(hv0.x, w2col[kk * 4 + 0], acc0);
                acc0 = fmaf(hv0.y, w2col[kk * 4 + 1], acc0);
                acc0 = fmaf(hv0.z, w2col[kk * 4 + 2], acc0);
                acc0 = fmaf(hv0.w, w2col[kk * 4 + 3], acc0);
            }
            gmax = fmaxf(gmax, fmaxf(acc0, 0.2f * acc0));
        }
        __syncthreads();   // protect h1s for next tile's phase A
    }

    // ---- global feats: each j owned by exactly one thread ----
    din[tid] = fmaxf(gmax, NEGF);
    if (tid < 4) din[128 + tid] = conds[b * 4 + tid];
    __syncthreads();

    // ---- decision net: one output per thread ----
    float g = b3[tid];
    #pragma unroll 4
    for (int i = 0; i < 132; ++i)
        g = fmaf(din[i], w3[i * 128 + tid], g);
    g = fmaxf(g, 0.2f * g);
    float part = g * w4[tid];
    #pragma unroll
    for (int s = 1; s < 64; s <<= 1)
        part += __shfl_xor(part, s, 64);
    if (lane == 0) red[wave] = part;
    __syncthreads();
    if (tid == 0) {
        float sc = (red[0] + red[1] + b4[0]) * scale;
        out[b] = fminf(fmaxf(sc, -1000.0f), 1000.0f);
    }
}

extern "C" void kernel_launch(void* const* d_in, const int* in_sizes, int n_in,
                              void* d_out, int out_size, void* d_ws, size_t ws_size,
                              hipStream_t stream) {
    const float* muons = (const float*)d_in[0];
    const int*   bidx  = (const int*)d_in[1];
    const float* conds = (const float*)d_in[2];
    // d_in[3] = batch_size scalar (derive B from conditions instead)
    const float* w1 = (const float*)d_in[4];
    const float* b1 = (const float*)d_in[5];
    const float* w2 = (const float*)d_in[6];
    const float* b2 = (const float*)d_in[7];
    const float* w3 = (const float*)d_in[8];
    const float* b3 = (const float*)d_in[9];
    const float* w4 = (const float*)d_in[10];
    const float* b4 = (const float*)d_in[11];

    const int M = in_sizes[0] / 3;
    const int B = in_sizes[2] / 4;
    int* seg = (int*)d_ws;  // (B+1) ints
    const float scale = 1.0f / fmaxf(1.0f, sqrtf((float)B));

    seg_bounds_kernel<<<(M + 255) / 256, 256, 0, stream>>>(bidx, M, B, seg);
    critic_kernel<<<B, 128, 0, stream>>>(muons, conds, seg,
                                         w1, b1, w2, b2, w3, b3, w4, b4,
                                         (float*)d_out, scale);
}

// Round 6
// 343.907 us; speedup vs baseline: 8.1533x; 1.9744x over previous
//
#include <hip/hip_runtime.h>
#include <math.h>

#define NEGF (-1.0e9f)

typedef __attribute__((ext_vector_type(8))) short short8;
typedef __attribute__((ext_vector_type(4))) float f32x4;

static __device__ __forceinline__ unsigned short bf16_rne(float f) {
    unsigned int u = __float_as_uint(f);
    u += 0x7FFFu + ((u >> 16) & 1u);
    return (unsigned short)(u >> 16);
}

// Kernel A: segment boundaries from sorted batch_index.
__global__ void seg_bounds_kernel(const int* __restrict__ bi, int M, int B,
                                  int* __restrict__ seg) {
    int m = blockIdx.x * blockDim.x + threadIdx.x;
    if (m >= M) return;
    int cur = bi[m];
    if (m == 0) {
        for (int b = 0; b <= cur; ++b) seg[b] = 0;
    } else {
        int prev = bi[m - 1];
        for (int b = prev + 1; b <= cur; ++b) seg[b] = m;
    }
    if (m == M - 1) {
        for (int b = cur + 1; b <= B; ++b) seg[b] = M;
    }
}

// Kernel P: split w2 [64 k][128 col] into hi/lo bf16, laid out in the exact
// per-lane MFMA B-fragment order so critic loads 1 dwordx4 per fragment.
// ushort layout: [cg 8][ks 2][p 2][slot 64][e 8], slot = kg*16+lane16,
// value = bf16split_p(w2[ks*32+kg*8+e][cg*16+lane16]).
__global__ void prep_w2_kernel(const float* __restrict__ w2,
                               unsigned short* __restrict__ wf) {
    int t = blockIdx.x * blockDim.x + threadIdx.x;   // 0..8191
    if (t >= 8192) return;
    int e = t & 7, slot = (t >> 3) & 63, ks = (t >> 9) & 1, cg = t >> 10;
    int lane16 = slot & 15, kg = slot >> 4;
    int k = ks * 32 + kg * 8 + e;
    int col = cg * 16 + lane16;
    float w = w2[k * 128 + col];
    unsigned ub = __float_as_uint(w);
    unsigned short hi = (unsigned short)(ub >> 16);               // trunc
    float lof = w - __uint_as_float(ub & 0xFFFF0000u);
    unsigned short lo = bf16_rne(lof);
    wf[((cg * 2 + ks) * 2 + 0) * 512 + slot * 8 + e] = hi;
    wf[((cg * 2 + ks) * 2 + 1) * 512 + slot * 8 + e] = lo;
}

// One 128-thread block (2 waves) per batch.
// Phase A (fp32 VALU): layer-1 -> leaky -> split hi/lo bf16 -> swizzled LDS
//   A-tile [2 planes][64 rows][64 k] bf16 (byte ^= (row&7)<<4 : kills the
//   stride-128B bank conflict on both write and read sides).
// Phase B (MFMA): 3-pass split-bf16 16x16x32; wave w owns cols w*64..+63,
//   4x4 fragment grid, w2 fragments resident in 64 VGPRs (from prep kernel).
//   Leaky+bias DEFERRED past the segment max (both monotone/per-col uniform)
//   so per-tile epilogue is cndmask+fmax only.
__global__ __launch_bounds__(128, 2) void critic_kernel(
    const float* __restrict__ muons,   // [M,3]
    const float* __restrict__ conds,   // [B,4]
    const int*   __restrict__ seg,     // [B+1]
    const float* __restrict__ w1,      // [7,64]
    const float* __restrict__ b1,      // [64]
    const unsigned short* __restrict__ w2frag,  // packed by prep_w2_kernel
    const float* __restrict__ b2,      // [128]
    const float* __restrict__ w3,      // [132,128]
    const float* __restrict__ b3,      // [128]
    const float* __restrict__ w4,      // [128]
    const float* __restrict__ b4,      // [1]
    float* __restrict__ out,           // [B]
    float scale)
{
    __shared__ __align__(16) float w1t[64 * 8];  // [k][i], i<7: w1[i][k], i==7: b1[k]
    __shared__ __align__(16) char  alds[2][8192]; // [p][row 64][k 64] bf16, swizzled
    __shared__ float din[132];
    __shared__ float red[2];

    const int tid  = threadIdx.x;
    const int b    = blockIdx.x;
    const int wave = tid >> 6;
    const int lane = tid & 63;
    const int l16  = lane & 15;
    const int lkg  = lane >> 4;

    // ---- stage w1(+b1) into LDS ----
    for (int idx = tid; idx < 512; idx += 128) {
        int k = idx >> 3, i = idx & 7;
        w1t[idx] = (i < 7) ? w1[i * 64 + k] : b1[k];
    }

    // ---- B-fragments (w2 hi/lo) into registers: 16 x dwordx4 ----
    short8 bhi[4][2], blo[4][2];
    {
        const short8* wf = (const short8*)w2frag;   // 16B granules
        const int slot = lkg * 16 + l16;
        #pragma unroll
        for (int ct = 0; ct < 4; ++ct) {
            const int cg = wave * 4 + ct;
            #pragma unroll
            for (int ks = 0; ks < 2; ++ks) {
                bhi[ct][ks] = wf[((cg * 2 + ks) * 2 + 0) * 64 + slot];
                blo[ct][ks] = wf[((cg * 2 + ks) * 2 + 1) * 64 + slot];
            }
        }
    }

    const float c0 = conds[b * 4 + 0];
    const float c1 = conds[b * 4 + 1];
    const float c2 = conds[b * 4 + 2];
    const float c3 = conds[b * 4 + 3];

    __syncthreads();

    const int start = seg[b];
    const int end   = seg[b + 1];

    float gmax[4];
    #pragma unroll
    for (int ct = 0; ct < 4; ++ct) gmax[ct] = NEGF;

    const int mslot = tid >> 1;   // muon slot 0..63
    const int half  = tid & 1;    // k-half (0: k 0..31, 1: k 32..63)

    for (int m0 = start; m0 < end; m0 += 64) {
        const int cnt = min(64, end - m0);

        // ---- phase A: layer 1, split, pack, swizzled LDS write ----
        if (mslot < cnt) {
            const int gm = m0 + mslot;
            const float x0 = muons[gm * 3 + 0];
            const float x1 = muons[gm * 3 + 1];
            const float x2 = muons[gm * 3 + 2];
            const unsigned swz = (unsigned)((mslot & 7) << 4);
            #pragma unroll
            for (int g = 0; g < 4; ++g) {
                float hv[8];
                #pragma unroll
                for (int u = 0; u < 8; ++u) {
                    const float* wk = &w1t[(half * 32 + g * 8 + u) * 8];
                    float s = wk[7];
                    s = fmaf(x0, wk[0], s);
                    s = fmaf(x1, wk[1], s);
                    s = fmaf(x2, wk[2], s);
                    s = fmaf(c0, wk[3], s);
                    s = fmaf(c1, wk[4], s);
                    s = fmaf(c2, wk[5], s);
                    s = fmaf(c3, wk[6], s);
                    hv[u] = fmaxf(s, 0.2f * s);
                }
                short8 vhi, vlo;
                #pragma unroll
                for (int u = 0; u < 8; ++u) {
                    unsigned ub = __float_as_uint(hv[u]);
                    vhi[u] = (short)(ub >> 16);
                    float lof = hv[u] - __uint_as_float(ub & 0xFFFF0000u);
                    vlo[u] = (short)bf16_rne(lof);
                }
                const unsigned addr =
                    ((unsigned)(mslot * 128 + half * 64 + g * 16)) ^ swz;
                *(short8*)(&alds[0][addr]) = vhi;
                *(short8*)(&alds[1][addr]) = vlo;
            }
        }
        __syncthreads();

        // ---- phase B: 3-pass split-bf16 MFMA, 4x4 fragments ----
        f32x4 acc[4][4];
        #pragma unroll
        for (int rt = 0; rt < 4; ++rt)
            #pragma unroll
            for (int ct = 0; ct < 4; ++ct)
                acc[rt][ct] = (f32x4){0.f, 0.f, 0.f, 0.f};

        #pragma unroll
        for (int rt = 0; rt < 4; ++rt) {
            const int row = rt * 16 + l16;
            const unsigned base =
                ((unsigned)(row * 128 + lkg * 16)) ^ ((unsigned)((row & 7) << 4));
            const short8 ah0 = *(const short8*)(&alds[0][base]);
            const short8 ah1 = *(const short8*)(&alds[0][base ^ 64u]);
            const short8 al0 = *(const short8*)(&alds[1][base]);
            const short8 al1 = *(const short8*)(&alds[1][base ^ 64u]);
            #pragma unroll
            for (int ct = 0; ct < 4; ++ct) {
                f32x4 c = acc[rt][ct];
                c = __builtin_amdgcn_mfma_f32_16x16x32_bf16(ah0, bhi[ct][0], c, 0, 0, 0);
                c = __builtin_amdgcn_mfma_f32_16x16x32_bf16(ah1, bhi[ct][1], c, 0, 0, 0);
                c = __builtin_amdgcn_mfma_f32_16x16x32_bf16(al0, bhi[ct][0], c, 0, 0, 0);
                c = __builtin_amdgcn_mfma_f32_16x16x32_bf16(al1, bhi[ct][1], c, 0, 0, 0);
                c = __builtin_amdgcn_mfma_f32_16x16x32_bf16(ah0, blo[ct][0], c, 0, 0, 0);
                c = __builtin_amdgcn_mfma_f32_16x16x32_bf16(ah1, blo[ct][1], c, 0, 0, 0);
                acc[rt][ct] = c;
            }
        }

        // ---- epilogue: mask inactive rows, fold raw max ----
        #pragma unroll
        for (int rt = 0; rt < 4; ++rt) {
            #pragma unroll
            for (int j = 0; j < 4; ++j) {
                const int row = rt * 16 + lkg * 4 + j;
                const bool act = row < cnt;
                gmax[0] = fmaxf(gmax[0], act ? acc[rt][0][j] : NEGF);
                gmax[1] = fmaxf(gmax[1], act ? acc[rt][1][j] : NEGF);
                gmax[2] = fmaxf(gmax[2], act ? acc[rt][2][j] : NEGF);
                gmax[3] = fmaxf(gmax[3], act ? acc[rt][3][j] : NEGF);
            }
        }
        __syncthreads();   // protect alds for next tile's phase A
    }

    // ---- cross-lane max (rows are spread over lane>>4 groups) ----
    #pragma unroll
    for (int ct = 0; ct < 4; ++ct) {
        float v = gmax[ct];
        v = fmaxf(v, __shfl_xor(v, 16, 64));
        v = fmaxf(v, __shfl_xor(v, 32, 64));
        if (lane < 16) {
            const int col = wave * 64 + ct * 16 + lane;
            const float biased = v + b2[col];
            const float actv = fmaxf(biased, 0.2f * biased);   // deferred leaky
            din[col] = (start < end) ? actv : NEGF;            // empty-segment guard
        }
    }
    if (tid < 4) din[128 + tid] = conds[b * 4 + tid];
    __syncthreads();

    // ---- decision net: one output column per thread ----
    float g = b3[tid];
    #pragma unroll 4
    for (int i = 0; i < 132; ++i)
        g = fmaf(din[i], w3[i * 128 + tid], g);
    g = fmaxf(g, 0.2f * g);
    float part = g * w4[tid];
    #pragma unroll
    for (int s = 1; s < 64; s <<= 1)
        part += __shfl_xor(part, s, 64);
    if (lane == 0) red[wave] = part;
    __syncthreads();
    if (tid == 0) {
        float sc = (red[0] + red[1] + b4[0]) * scale;
        out[b] = fminf(fmaxf(sc, -1000.0f), 1000.0f);
    }
}

extern "C" void kernel_launch(void* const* d_in, const int* in_sizes, int n_in,
                              void* d_out, int out_size, void* d_ws, size_t ws_size,
                              hipStream_t stream) {
    const float* muons = (const float*)d_in[0];
    const int*   bidx  = (const int*)d_in[1];
    const float* conds = (const float*)d_in[2];
    // d_in[3] = batch_size scalar (derive B from conditions instead)
    const float* w1 = (const float*)d_in[4];
    const float* b1 = (const float*)d_in[5];
    const float* w2 = (const float*)d_in[6];
    const float* b2 = (const float*)d_in[7];
    const float* w3 = (const float*)d_in[8];
    const float* b3 = (const float*)d_in[9];
    const float* w4 = (const float*)d_in[10];
    const float* b4 = (const float*)d_in[11];

    const int M = in_sizes[0] / 3;
    const int B = in_sizes[2] / 4;
    int* seg = (int*)d_ws;                                   // (B+1) ints
    const size_t off = (((size_t)(B + 1)) * 4 + 255) & ~(size_t)255;
    unsigned short* w2frag = (unsigned short*)((char*)d_ws + off);  // 32 KB
    const float scale = 1.0f / fmaxf(1.0f, sqrtf((float)B));

    seg_bounds_kernel<<<(M + 255) / 256, 256, 0, stream>>>(bidx, M, B, seg);
    prep_w2_kernel<<<32, 256, 0, stream>>>(w2, w2frag);
    critic_kernel<<<B, 128, 0, stream>>>(muons, conds, seg,
                                         w1, b1, w2frag, b2, w3, b3, w4, b4,
                                         (float*)d_out, scale);
}

// Round 7
// 280.193 us; speedup vs baseline: 10.0073x; 1.2274x over previous
//
#include <hip/hip_runtime.h>
#include <math.h>

#define NEGF (-1.0e9f)
#define NB 4   // batches per block

typedef __attribute__((ext_vector_type(8))) short short8;
typedef __attribute__((ext_vector_type(4))) float f32x4;

static __device__ __forceinline__ unsigned short bf16_rne(float f) {
    unsigned int u = __float_as_uint(f);
    u += 0x7FFFu + ((u >> 16) & 1u);
    return (unsigned short)(u >> 16);
}

// Kernel A: segment boundaries from sorted batch_index.
__global__ void seg_bounds_kernel(const int* __restrict__ bi, int M, int B,
                                  int* __restrict__ seg) {
    int m = blockIdx.x * blockDim.x + threadIdx.x;
    if (m >= M) return;
    int cur = bi[m];
    if (m == 0) {
        for (int b = 0; b <= cur; ++b) seg[b] = 0;
    } else {
        int prev = bi[m - 1];
        for (int b = prev + 1; b <= cur; ++b) seg[b] = m;
    }
    if (m == M - 1) {
        for (int b = cur + 1; b <= B; ++b) seg[b] = M;
    }
}

// Kernel P: split w2 [64 k][128 col] into hi/lo bf16 in per-lane MFMA
// B-fragment order. ushort layout: [cg 8][ks 2][p 2][slot 64][e 8],
// slot = kg*16+lane16, value = bf16split_p(w2[ks*32+kg*8+e][cg*16+lane16]).
__global__ void prep_w2_kernel(const float* __restrict__ w2,
                               unsigned short* __restrict__ wf) {
    int t = blockIdx.x * blockDim.x + threadIdx.x;   // 0..8191
    if (t >= 8192) return;
    int e = t & 7, slot = (t >> 3) & 63, ks = (t >> 9) & 1, cg = t >> 10;
    int lane16 = slot & 15, kg = slot >> 4;
    int k = ks * 32 + kg * 8 + e;
    int col = cg * 16 + lane16;
    float w = w2[k * 128 + col];
    unsigned ub = __float_as_uint(w);
    unsigned short hi = (unsigned short)(ub >> 16);               // trunc
    float lof = w - __uint_as_float(ub & 0xFFFF0000u);
    unsigned short lo = bf16_rne(lof);
    wf[((cg * 2 + ks) * 2 + 0) * 512 + slot * 8 + e] = hi;
    wf[((cg * 2 + ks) * 2 + 1) * 512 + slot * 8 + e] = lo;
}

// One 64-thread (1-wave) block, NB consecutive batches per block.
// The wave is SELF-SUFFICIENT: it holds all 128 w2 columns (hi+lo) in
// 128 VGPRs, computes layer-1 for its own 32-row tile into wave-private
// LDS, and MFMAs against all columns. Within a wave, LDS write->read is
// ordered by lgkmcnt, so the main loop has ZERO barriers (R6's 2-wave
// tile barriers at 1.75 waves/SIMD were the stall source: 52% combined
// pipe util). Stall hiding comes from the sibling wave on the SIMD
// (2 waves/SIMD at ~220 VGPR). NB=4 amortizes the w2frag/w1t prologue.
__global__ __launch_bounds__(64, 2) void critic_kernel(
    const float* __restrict__ muons,   // [M,3]
    const float* __restrict__ conds,   // [B,4]
    const int*   __restrict__ seg,     // [B+1]
    const float* __restrict__ w1,      // [7,64]
    const float* __restrict__ b1,      // [64]
    const unsigned short* __restrict__ w2frag,  // packed by prep_w2_kernel
    const float* __restrict__ b2,      // [128]
    const float* __restrict__ w3,      // [132,128]
    const float* __restrict__ b3,      // [128]
    const float* __restrict__ w4,      // [128]
    const float* __restrict__ b4,      // [1]
    float* __restrict__ out,           // [B]
    float scale, int Btot)
{
    __shared__ __align__(16) float w1t[64 * 8];  // [k][i], i<7: w1[i][k], i==7: b1[k]
    __shared__ __align__(16) char  alds[2][4096]; // [p][row 32][k 64] bf16, swizzled
    __shared__ float din[132];

    const int tid = threadIdx.x;      // == lane, 0..63
    const int l16 = tid & 15;
    const int lkg = tid >> 4;

    // ---- stage w1(+b1) into LDS ----
    for (int idx = tid; idx < 512; idx += 64) {
        int k = idx >> 3, i = idx & 7;
        w1t[idx] = (i < 7) ? w1[i * 64 + k] : b1[k];
    }

    // ---- ALL 8 col-groups of w2 hi/lo into registers: 32 x dwordx4 ----
    short8 bhi[8][2], blo[8][2];
    {
        const short8* wf = (const short8*)w2frag;   // 16B granules
        #pragma unroll
        for (int cg = 0; cg < 8; ++cg) {
            #pragma unroll
            for (int ks = 0; ks < 2; ++ks) {
                bhi[cg][ks] = wf[((cg * 2 + ks) * 2 + 0) * 64 + tid];
                blo[cg][ks] = wf[((cg * 2 + ks) * 2 + 1) * 64 + tid];
            }
        }
    }
    __syncthreads();   // trivial for 1 wave; keeps w1t ordering explicit

    const int mslot = tid >> 1;   // muon slot 0..31
    const int half  = tid & 1;    // k-half (0: k 0..31, 1: k 32..63)

    for (int bi = 0; bi < NB; ++bi) {
        const int b = blockIdx.x * NB + bi;
        if (b >= Btot) break;

        const float c0 = conds[b * 4 + 0];
        const float c1 = conds[b * 4 + 1];
        const float c2 = conds[b * 4 + 2];
        const float c3 = conds[b * 4 + 3];
        const int start = seg[b];
        const int end   = seg[b + 1];

        float gmax[8];
        #pragma unroll
        for (int cg = 0; cg < 8; ++cg) gmax[cg] = NEGF;

        for (int m0 = start; m0 < end; m0 += 32) {
            const int cnt = min(32, end - m0);

            // ---- phase A: layer 1, split hi/lo, swizzled LDS write ----
            if (mslot < cnt) {
                const int gm = m0 + mslot;
                const float x0 = muons[gm * 3 + 0];
                const float x1 = muons[gm * 3 + 1];
                const float x2 = muons[gm * 3 + 2];
                const unsigned swz = (unsigned)((mslot & 7) << 4);
                #pragma unroll
                for (int g = 0; g < 4; ++g) {
                    float hv[8];
                    #pragma unroll
                    for (int u = 0; u < 8; ++u) {
                        const float* wk = &w1t[(half * 32 + g * 8 + u) * 8];
                        float s = wk[7];
                        s = fmaf(x0, wk[0], s);
                        s = fmaf(x1, wk[1], s);
                        s = fmaf(x2, wk[2], s);
                        s = fmaf(c0, wk[3], s);
                        s = fmaf(c1, wk[4], s);
                        s = fmaf(c2, wk[5], s);
                        s = fmaf(c3, wk[6], s);
                        hv[u] = fmaxf(s, 0.2f * s);
                    }
                    short8 vhi, vlo;
                    #pragma unroll
                    for (int u = 0; u < 8; ++u) {
                        unsigned ub = __float_as_uint(hv[u]);
                        vhi[u] = (short)(ub >> 16);
                        float lof = hv[u] - __uint_as_float(ub & 0xFFFF0000u);
                        vlo[u] = (short)bf16_rne(lof);
                    }
                    const unsigned addr =
                        ((unsigned)(mslot * 128 + half * 64 + g * 16)) ^ swz;
                    *(short8*)(&alds[0][addr]) = vhi;
                    *(short8*)(&alds[1][addr]) = vlo;
                }
            }
            // no barrier: same-wave ds_write -> ds_read ordered by lgkmcnt

            // ---- phase B: 3-pass split-bf16 MFMA over 2 row-tiles ----
            #pragma unroll
            for (int rt = 0; rt < 2; ++rt) {
                const int row = rt * 16 + l16;
                const unsigned base =
                    ((unsigned)(row * 128 + lkg * 16)) ^ ((unsigned)((row & 7) << 4));
                const short8 ah0 = *(const short8*)(&alds[0][base]);
                const short8 ah1 = *(const short8*)(&alds[0][base ^ 64u]);
                const short8 al0 = *(const short8*)(&alds[1][base]);
                const short8 al1 = *(const short8*)(&alds[1][base ^ 64u]);

                f32x4 acc[8];
                #pragma unroll
                for (int cg = 0; cg < 8; ++cg) {
                    f32x4 c = (f32x4){0.f, 0.f, 0.f, 0.f};
                    c = __builtin_amdgcn_mfma_f32_16x16x32_bf16(ah0, bhi[cg][0], c, 0, 0, 0);
                    c = __builtin_amdgcn_mfma_f32_16x16x32_bf16(ah1, bhi[cg][1], c, 0, 0, 0);
                    c = __builtin_amdgcn_mfma_f32_16x16x32_bf16(al0, bhi[cg][0], c, 0, 0, 0);
                    c = __builtin_amdgcn_mfma_f32_16x16x32_bf16(al1, bhi[cg][1], c, 0, 0, 0);
                    c = __builtin_amdgcn_mfma_f32_16x16x32_bf16(ah0, blo[cg][0], c, 0, 0, 0);
                    c = __builtin_amdgcn_mfma_f32_16x16x32_bf16(ah1, blo[cg][1], c, 0, 0, 0);
                    acc[cg] = c;
                }

                // fold raw max (bias/leaky deferred past max)
                #pragma unroll
                for (int j = 0; j < 4; ++j) {
                    const int rowo = rt * 16 + lkg * 4 + j;
                    const bool act = rowo < cnt;
                    #pragma unroll
                    for (int cg = 0; cg < 8; ++cg)
                        gmax[cg] = fmaxf(gmax[cg], act ? acc[cg][j] : NEGF);
                }
            }
        }

        // ---- cross-lane max over row-groups (lkg), then din ----
        #pragma unroll
        for (int cg = 0; cg < 8; ++cg) {
            float v = gmax[cg];
            v = fmaxf(v, __shfl_xor(v, 16, 64));
            v = fmaxf(v, __shfl_xor(v, 32, 64));
            if (tid < 16) {
                const int col = cg * 16 + tid;
                const float biased = v + b2[col];
                const float actv = fmaxf(biased, 0.2f * biased);  // deferred leaky
                din[col] = (start < end) ? actv : NEGF;           // empty-seg guard
            }
        }
        if (tid < 4) din[128 + tid] = conds[b * 4 + tid];
        // same-wave LDS ordering: no barrier needed

        // ---- decision net: 2 output columns per thread ----
        float g0 = b3[tid];
        float g1 = b3[64 + tid];
        #pragma unroll 4
        for (int i = 0; i < 132; ++i) {
            const float d = din[i];
            g0 = fmaf(d, w3[i * 128 + tid], g0);
            g1 = fmaf(d, w3[i * 128 + 64 + tid], g1);
        }
        g0 = fmaxf(g0, 0.2f * g0);
        g1 = fmaxf(g1, 0.2f * g1);
        float part = g0 * w4[tid] + g1 * w4[64 + tid];
        #pragma unroll
        for (int s = 1; s < 64; s <<= 1)
            part += __shfl_xor(part, s, 64);
        if (tid == 0) {
            float sc = (part + b4[0]) * scale;
            out[b] = fminf(fmaxf(sc, -1000.0f), 1000.0f);
        }
    }
}

extern "C" void kernel_launch(void* const* d_in, const int* in_sizes, int n_in,
                              void* d_out, int out_size, void* d_ws, size_t ws_size,
                              hipStream_t stream) {
    const float* muons = (const float*)d_in[0];
    const int*   bidx  = (const int*)d_in[1];
    const float* conds = (const float*)d_in[2];
    // d_in[3] = batch_size scalar (derive B from conditions instead)
    const float* w1 = (const float*)d_in[4];
    const float* b1 = (const float*)d_in[5];
    const float* w2 = (const float*)d_in[6];
    const float* b2 = (const float*)d_in[7];
    const float* w3 = (const float*)d_in[8];
    const float* b3 = (const float*)d_in[9];
    const float* w4 = (const float*)d_in[10];
    const float* b4 = (const float*)d_in[11];

    const int M = in_sizes[0] / 3;
    const int B = in_sizes[2] / 4;
    int* seg = (int*)d_ws;                                   // (B+1) ints
    const size_t off = (((size_t)(B + 1)) * 4 + 255) & ~(size_t)255;
    unsigned short* w2frag = (unsigned short*)((char*)d_ws + off);  // 32 KB
    const float scale = 1.0f / fmaxf(1.0f, sqrtf((float)B));

    seg_bounds_kernel<<<(M + 255) / 256, 256, 0, stream>>>(bidx, M, B, seg);
    prep_w2_kernel<<<32, 256, 0, stream>>>(w2, w2frag);
    const int nblk = (B + NB - 1) / NB;
    critic_kernel<<<nblk, 64, 0, stream>>>(muons, conds, seg,
                                           w1, b1, w2frag, b2, w3, b3, w4, b4,
                                           (float*)d_out, scale, B);
}